// Round 7
// baseline (5631.448 us; speedup 1.0000x reference)
//
#include <hip/hip_runtime.h>
#include <cstdint>
#include <cstddef>

using bf16 = __bf16;
typedef float f32x4 __attribute__((ext_vector_type(4)));
typedef bf16 bf16x8 __attribute__((ext_vector_type(8)));
typedef bf16 bf16x4 __attribute__((ext_vector_type(4)));

#define NB 4           // batch
#define SEQ 2048
#define DM 1024        // d_model
#define HD 4096        // hidden
#define SD (SEQ*DM)    // 2^21 elems per sample

__device__ __forceinline__ float geluf(float v) {
    return 0.5f * v * (1.0f + erff(v * 0.70710678118654752f));
}

// ---------------------------------------------------------------------------
// Universal NT GEMM: C[m][n] = sum_k A[m][k]*Bt[n][k] (+bias[n]) (+epilogue)
// A: M x K row-major bf16, Bt: N x K row-major bf16 (both K-contiguous).
// Tile 128x128x64, 4 waves, 16x16x32 bf16 MFMA, global_load_lds staging with
// chunk XOR swizzle (c' = c ^ (m&7)) on BOTH the global source and the
// ds_read address (both-sides involution).
// SPLIT: 3 accumulation passes (Ah*Bh + Al*Bh + Ah*Bl) ~ 17-bit-mantissa.
// EPI: 0 = f32 store, 1 = f32 gelu store,
//      4 = split bf16 (hi+lo) store, 5 = split bf16 transposed store (V^T)
// ---------------------------------------------------------------------------
template<int EPI, bool BIAS, bool SPLIT>
__global__ __launch_bounds__(256, 2) void gemm_nt(
    const bf16* __restrict__ Ah, const bf16* __restrict__ Al,
    const bf16* __restrict__ Bh, const bf16* __restrict__ Bl,
    const float* __restrict__ bias, void* __restrict__ Cg, void* __restrict__ Cl,
    const int K, const int ldc)
{
    __shared__ __align__(16) bf16 smA[128 * 64];
    __shared__ __align__(16) bf16 smB[128 * 64];

    const int tid  = threadIdx.x;
    const int lane = tid & 63;
    const int wave = tid >> 6;
    const int wr   = (wave >> 1) << 6;
    const int wc   = (wave & 1) << 6;
    const int l15  = lane & 15;
    const int q4   = lane >> 4;

    const long aoff = (long)blockIdx.x * 128 * K;
    const long boff = (long)blockIdx.y * 128 * K;

    int srow[4], scol[4];
#pragma unroll
    for (int it = 0; it < 4; ++it) {
        int chunk = it * 256 + tid;
        int m = chunk >> 3;
        srow[it] = m;
        scol[it] = ((chunk & 7) ^ (m & 7)) * 8;
    }

    f32x4 acc[4][4] = {};

#pragma unroll
    for (int p = 0; p < (SPLIT ? 3 : 1); ++p) {
        const bf16* Ab = (SPLIT && p == 1 ? Al : Ah) + aoff;
        const bf16* Bb = (SPLIT && p == 2 ? Bl : Bh) + boff;

        for (int k0 = 0; k0 < K; k0 += 64) {
#pragma unroll
            for (int it = 0; it < 4; ++it) {
                const bf16* ga = Ab + (long)srow[it] * K + (k0 + scol[it]);
                const bf16* gb = Bb + (long)srow[it] * K + (k0 + scol[it]);
                bf16* la = smA + (size_t)(it * 256 + (wave << 6)) * 8;  // linear fill
                bf16* lb = smB + (size_t)(it * 256 + (wave << 6)) * 8;
                __builtin_amdgcn_global_load_lds(
                    (const __attribute__((address_space(1))) void*)ga,
                    (__attribute__((address_space(3))) void*)la, 16, 0, 0);
                __builtin_amdgcn_global_load_lds(
                    (const __attribute__((address_space(1))) void*)gb,
                    (__attribute__((address_space(3))) void*)lb, 16, 0, 0);
            }
            __syncthreads();   // compiler drains vmcnt(0) before barrier

#pragma unroll
            for (int kk = 0; kk < 2; ++kk) {
                bf16x8 av[4], bv[4];
#pragma unroll
                for (int i = 0; i < 4; ++i) {
                    const int rowa = wr + i * 16 + l15;
                    const int ca = (kk * 4 + q4) ^ (rowa & 7);   // swizzled read
                    av[i] = *(const bf16x8*)(smA + rowa * 64 + ca * 8);
                    const int rowb = wc + i * 16 + l15;
                    const int cb = (kk * 4 + q4) ^ (rowb & 7);
                    bv[i] = *(const bf16x8*)(smB + rowb * 64 + cb * 8);
                }
#pragma unroll
                for (int i = 0; i < 4; ++i)
#pragma unroll
                    for (int j = 0; j < 4; ++j)
                        acc[i][j] = __builtin_amdgcn_mfma_f32_16x16x32_bf16(
                            av[i], bv[j], acc[i][j], 0, 0, 0);
            }
            __syncthreads();
        }
    }

    // epilogue: D col = lane&15, row = (lane>>4)*4 + e
    const int gcol0 = blockIdx.y * 128 + wc + l15;
    const int grow0 = blockIdx.x * 128 + wr + q4 * 4;
#pragma unroll
    for (int j = 0; j < 4; ++j) {
        const int col = gcol0 + j * 16;
        const float bvz = BIAS ? bias[col] : 0.0f;
#pragma unroll
        for (int i = 0; i < 4; ++i) {
            const int row = grow0 + i * 16;
            if (EPI == 5) {
                bf16x4 oh, ol;
#pragma unroll
                for (int e = 0; e < 4; ++e) {
                    const float v = acc[i][j][e] + bvz;
                    const bf16 hi = (bf16)v;
                    oh[e] = hi;
                    ol[e] = (bf16)(v - (float)hi);
                }
                *(bf16x4*)((bf16*)Cg + (long)col * ldc + row) = oh;
                *(bf16x4*)((bf16*)Cl + (long)col * ldc + row) = ol;
            } else {
#pragma unroll
                for (int e = 0; e < 4; ++e) {
                    float v = acc[i][j][e] + bvz;
                    if (EPI == 1) v = geluf(v);
                    const long off = (long)(row + e) * ldc + col;
                    if (EPI == 4) {
                        const bf16 hi = (bf16)v;
                        ((bf16*)Cg)[off] = hi;
                        ((bf16*)Cl)[off] = (bf16)(v - (float)hi);
                    } else {
                        ((float*)Cg)[off] = v;
                    }
                }
            }
        }
    }
}

// ---------------------------------------------------------------------------
// y = emb[x] (f32) + sinusoidal pos; writes f32 residual + split bf16 (hi,lo)
// ---------------------------------------------------------------------------
__global__ __launch_bounds__(256) void embed_k(
    const int* __restrict__ x, const float* __restrict__ emb,
    float* __restrict__ yf, bf16* __restrict__ yh, bf16* __restrict__ yl)
{
    const int bs = blockIdx.x;          // B*S
    const int s = bs & (SEQ - 1);
    const long e0 = (long)x[bs] * DM;
    const int d = threadIdx.x * 4;
    const float4 ev = *(const float4*)(emb + e0 + d);
    float o[4];
    const float fs = (float)s;
#pragma unroll
    for (int e = 0; e < 4; ++e) {
        const int dd = d + e;
        const float div = powf(10000.0f, (float)dd * (1.0f / 1024.0f));
        const float ang = fs / div;
        const float p = (dd & 1) ? cosf(ang) : sinf(ang);
        o[e] = ((const float*)&ev)[e] + p;
    }
    *(float4*)(yf + (long)bs * DM + d) = *(float4*)o;
    bf16x4 oh, ol;
#pragma unroll
    for (int e = 0; e < 4; ++e) {
        oh[e] = (bf16)o[e];
        ol[e] = (bf16)(o[e] - (float)oh[e]);
    }
    *(bf16x4*)(yh + (long)bs * DM + d) = oh;
    *(bf16x4*)(yl + (long)bs * DM + d) = ol;
}

// ---------------------------------------------------------------------------
// f32 -> split bf16 transpose: src R x C (f32) -> dst C x R (hi, lo)
// ---------------------------------------------------------------------------
__global__ __launch_bounds__(256) void transpose_k(
    const float* __restrict__ src, bf16* __restrict__ dsth, bf16* __restrict__ dstl,
    int R, int C)
{
    __shared__ bf16 th[64][65];
    __shared__ bf16 tl[64][65];
    const int c0 = blockIdx.x * 64, r0 = blockIdx.y * 64;
    const int t = threadIdx.x;
    const int tr = t >> 4;
    const int tc = (t & 15) * 4;
#pragma unroll
    for (int p = 0; p < 4; ++p) {
        const int r = tr + p * 16;
        const float4 v = *(const float4*)(src + (long)(r0 + r) * C + c0 + tc);
        const float vv[4] = {v.x, v.y, v.z, v.w};
#pragma unroll
        for (int e = 0; e < 4; ++e) {
            const bf16 hi = (bf16)vv[e];
            th[r][tc + e] = hi;
            tl[r][tc + e] = (bf16)(vv[e] - (float)hi);
        }
    }
    __syncthreads();
#pragma unroll
    for (int p = 0; p < 4; ++p) {
        const int c = tr + p * 16;
        bf16x4 oh, ol;
#pragma unroll
        for (int e = 0; e < 4; ++e) { oh[e] = th[tc + e][c]; ol[e] = tl[tc + e][c]; }
        *(bf16x4*)(dsth + (long)(c0 + c) * R + r0 + tc) = oh;
        *(bf16x4*)(dstl + (long)(c0 + c) * R + r0 + tc) = ol;
    }
}

// ---------------------------------------------------------------------------
// Row softmax: 2048 f32 per row -> split bf16 (hi, lo)
// ---------------------------------------------------------------------------
__global__ __launch_bounds__(256) void softmax_k(
    const float* __restrict__ S, bf16* __restrict__ Ph, bf16* __restrict__ Pl)
{
    const long row = blockIdx.x;
    const float4* src = (const float4*)(S + (row << 11));
    const int t = threadIdx.x;
    float4 a = src[t], b = src[256 + t];
    float m = fmaxf(fmaxf(fmaxf(a.x, a.y), fmaxf(a.z, a.w)),
                    fmaxf(fmaxf(b.x, b.y), fmaxf(b.z, b.w)));
#pragma unroll
    for (int o = 32; o; o >>= 1) m = fmaxf(m, __shfl_xor(m, o));
    __shared__ float red1[4], red2[4];
    const int wv = t >> 6;
    if ((t & 63) == 0) red1[wv] = m;
    __syncthreads();
    m = fmaxf(fmaxf(red1[0], red1[1]), fmaxf(red1[2], red1[3]));

    a.x = expf(a.x - m); a.y = expf(a.y - m); a.z = expf(a.z - m); a.w = expf(a.w - m);
    b.x = expf(b.x - m); b.y = expf(b.y - m); b.z = expf(b.z - m); b.w = expf(b.w - m);
    float s = a.x + a.y + a.z + a.w + b.x + b.y + b.z + b.w;
#pragma unroll
    for (int o = 32; o; o >>= 1) s += __shfl_xor(s, o);
    if ((t & 63) == 0) red2[wv] = s;
    __syncthreads();
    s = red2[0] + red2[1] + red2[2] + red2[3];
    const float inv = 1.0f / s;

    const float pv[8] = {a.x * inv, a.y * inv, a.z * inv, a.w * inv,
                         b.x * inv, b.y * inv, b.z * inv, b.w * inv};
    bf16x4 h0, l0, h1, l1;
#pragma unroll
    for (int e = 0; e < 4; ++e) {
        const bf16 hi = (bf16)pv[e];
        h0[e] = hi; l0[e] = (bf16)(pv[e] - (float)hi);
        const bf16 hj = (bf16)pv[4 + e];
        h1[e] = hj; l1[e] = (bf16)(pv[4 + e] - (float)hj);
    }
    *(bf16x4*)(Ph + (row << 11) + t * 4) = h0;
    *(bf16x4*)(Pl + (row << 11) + t * 4) = l0;
    *(bf16x4*)(Ph + (row << 11) + 1024 + t * 4) = h1;
    *(bf16x4*)(Pl + (row << 11) + 1024 + t * 4) = l1;
}

// ---------------------------------------------------------------------------
// LayerNorm over whole (S,D) sample: stats (2-stage, deterministic) + apply
// ---------------------------------------------------------------------------
__global__ __launch_bounds__(256) void ln_stats_k(
    const float* __restrict__ y, const float* __restrict__ r, float2* __restrict__ part)
{
    const int b = blockIdx.y;
    const long base = (long)b * SD + (long)blockIdx.x * (SD / 64);
    const float4* py = (const float4*)(y + base);
    const float4* pr = (const float4*)(r + base);
    float s = 0.f, q = 0.f;
    for (int i = threadIdx.x; i < (SD / 64) / 4; i += 256) {
        const float4 a = py[i], c = pr[i];
        const float x0 = a.x + c.x, x1 = a.y + c.y, x2 = a.z + c.z, x3 = a.w + c.w;
        s += x0 + x1 + x2 + x3;
        q += x0 * x0 + x1 * x1 + x2 * x2 + x3 * x3;
    }
#pragma unroll
    for (int o = 32; o; o >>= 1) { s += __shfl_xor(s, o); q += __shfl_xor(q, o); }
    __shared__ float rs[4], rq[4];
    const int wv = threadIdx.x >> 6;
    if ((threadIdx.x & 63) == 0) { rs[wv] = s; rq[wv] = q; }
    __syncthreads();
    if (threadIdx.x == 0)
        part[b * 64 + blockIdx.x] = make_float2(rs[0] + rs[1] + rs[2] + rs[3],
                                                rq[0] + rq[1] + rq[2] + rq[3]);
}

__global__ void ln_fin_k(const float2* __restrict__ part, float2* __restrict__ stats)
{
    const int b = blockIdx.x;
    const float2 p = part[b * 64 + threadIdx.x];
    float s = p.x, q = p.y;
#pragma unroll
    for (int o = 32; o; o >>= 1) { s += __shfl_xor(s, o); q += __shfl_xor(q, o); }
    if (threadIdx.x == 0) {
        const float inv_n = 1.0f / (float)SD;
        const float mean = s * inv_n;
        const float var = fmaxf(q * inv_n - mean * mean, 0.f);
        stats[b] = make_float2(mean, rsqrtf(var + 1e-5f));
    }
}

__global__ __launch_bounds__(256) void ln_apply_k(
    const float* __restrict__ yin, const float* __restrict__ r,
    const float* __restrict__ w, const float* __restrict__ bb,
    const float2* __restrict__ stats,
    float* __restrict__ yout, bf16* __restrict__ yh, bf16* __restrict__ yl)
{
    const long i = ((long)blockIdx.x * 256 + threadIdx.x) * 4;
    const int smp = (int)(i >> 21);
    const long sd = i & (SD - 1);
    const float2 st = stats[smp];
    const float4 a = *(const float4*)(yin + i);
    const float4 c = *(const float4*)(r + i);
    const float4 wv = *(const float4*)(w + sd);
    const float4 bv = *(const float4*)(bb + sd);
    float o[4];
    o[0] = (a.x + c.x - st.x) * st.y * wv.x + bv.x;
    o[1] = (a.y + c.y - st.x) * st.y * wv.y + bv.y;
    o[2] = (a.z + c.z - st.x) * st.y * wv.z + bv.z;
    o[3] = (a.w + c.w - st.x) * st.y * wv.w + bv.w;
    *(float4*)(yout + i) = *(float4*)o;
    bf16x4 oh, ol;
#pragma unroll
    for (int e = 0; e < 4; ++e) {
        oh[e] = (bf16)o[e];
        ol[e] = (bf16)(o[e] - (float)oh[e]);
    }
    *(bf16x4*)(yh + i) = oh;
    *(bf16x4*)(yl + i) = ol;
}

// ---------------------------------------------------------------------------
extern "C" void kernel_launch(void* const* d_in, const int* in_sizes, int n_in,
                              void* d_out, int out_size, void* d_ws, size_t ws_size,
                              hipStream_t stream)
{
    (void)in_sizes; (void)n_in; (void)out_size; (void)ws_size;

    const int*   x    = (const int*)  d_in[0];
    const float* emb  = (const float*)d_in[1];
    const float* wq   = (const float*)d_in[2];
    const float* bq   = (const float*)d_in[3];
    const float* wk   = (const float*)d_in[4];
    const float* bk   = (const float*)d_in[5];
    const float* wv   = (const float*)d_in[6];
    const float* bv   = (const float*)d_in[7];
    const float* wo   = (const float*)d_in[8];
    const float* bo   = (const float*)d_in[9];
    const float* w1   = (const float*)d_in[10];
    const float* b1   = (const float*)d_in[11];
    const float* w2   = (const float*)d_in[12];
    const float* b2   = (const float*)d_in[13];
    const float* ln1w = (const float*)d_in[14];
    const float* ln1b = (const float*)d_in[15];
    const float* ln2w = (const float*)d_in[16];
    const float* ln2b = (const float*)d_in[17];

    // Workspace layout — peak ~369 MiB (≤384 MiB proven-safe band).
    char* ws = (char*)d_ws;
    const size_t MB = (size_t)1 << 20;
    float*  yf    = (float*)(ws);                  //  32 MiB f32 residual [8192][1024]
    bf16*   ybh   = (bf16*) (ws + 32  * MB);       //  16 MiB y hi
    bf16*   ybl   = (bf16*) (ws + 48  * MB);       //  16 MiB y lo
    bf16*   wT    = (bf16*) (ws + 64  * MB);       //  48 MiB: 6 x 8 MiB weight slots
    bf16*   atth  = (bf16*) (ws + 112 * MB);       //  64 MiB att hi [8192][4096]
    bf16*   attl  = (bf16*) (ws + 176 * MB);       //  64 MiB att lo
    // per-batch attention scratch (dead outside the batch loop):
    bf16*   qh    = (bf16*) (ws + 240 * MB);       //  16 MiB [2048][4096]
    bf16*   ql    = (bf16*) (ws + 256 * MB);       //  16 MiB
    bf16*   kh    = (bf16*) (ws + 272 * MB);       //  16 MiB
    bf16*   kl    = (bf16*) (ws + 288 * MB);       //  16 MiB
    bf16*   vTh   = (bf16*) (ws + 304 * MB);       //  16 MiB [4096][2048]
    bf16*   vTl   = (bf16*) (ws + 320 * MB);       //  16 MiB
    float*  scf   = (float*)(ws + 336 * MB);       //  16 MiB f32 [2048][2048]
    bf16*   pbh   = (bf16*) (ws + 352 * MB);       //   8 MiB probs hi
    bf16*   pbl   = (bf16*) (ws + 360 * MB);       //   8 MiB probs lo
    // post-loop f32 outputs (reuse dead per-batch region at 240):
    float*  attout= (float*)(ws + 240 * MB);       //  32 MiB f32 [8192][1024]
    float*  ffnf  = (float*)(ws + 240 * MB);       //  32 MiB f32 (attout dead by then)
    bf16*   hh    = atth;                          //  64 MiB h hi (att dead after O-proj)
    bf16*   hl    = attl;                          //  64 MiB h lo
    float2* part  = (float2*)(ws + 368 * MB);      //   2 KiB LN partials
    float2* stats = (float2*)(ws + 368 * MB + 65536);

    const long TSZ = (long)DM * HD;
    bf16* slot[6];
    for (int s = 0; s < 6; ++s) slot[s] = wT + (long)s * TSZ;

    embed_k<<<NB * SEQ, 256, 0, stream>>>(x, emb, yf, ybh, ybl);

    for (int l = 0; l < 2; ++l) {
        // ---- phase 1 weights: wq, wk, wv (split, K-contiguous) ----
        bf16 *wqH = slot[0], *wqL = slot[1], *wkH = slot[2], *wkL = slot[3],
             *wvH = slot[4], *wvL = slot[5];
        transpose_k<<<dim3(64, 16), 256, 0, stream>>>(wq + l * TSZ, wqH, wqL, DM, HD);
        transpose_k<<<dim3(64, 16), 256, 0, stream>>>(wk + l * TSZ, wkH, wkL, DM, HD);
        transpose_k<<<dim3(64, 16), 256, 0, stream>>>(wv + l * TSZ, wvH, wvL, DM, HD);

        // ---- attention, batch-looped (peak-memory control) ----
        for (int b = 0; b < NB; ++b) {
            const bf16* yh_b = ybh + (long)b * SD;
            const bf16* yl_b = ybl + (long)b * SD;
            // q,k: [2048x1024]@[4096x1024]^T -> split bf16
            gemm_nt<4, true, true><<<dim3(16, 32), 256, 0, stream>>>(
                yh_b, yl_b, wqH, wqL, bq + l * HD, qh, ql, DM, HD);
            gemm_nt<4, true, true><<<dim3(16, 32), 256, 0, stream>>>(
                yh_b, yl_b, wkH, wkL, bk + l * HD, kh, kl, DM, HD);
            // v, split transposed store -> vT [4096][2048] (hi, lo)
            gemm_nt<5, true, true><<<dim3(16, 32), 256, 0, stream>>>(
                yh_b, yl_b, wvH, wvL, bv + l * HD, vTh, vTl, DM, SEQ);
            // scores = q@k^T (split) -> f32 [2048][2048]
            gemm_nt<0, false, true><<<dim3(16, 16), 256, 0, stream>>>(
                qh, ql, kh, kl, nullptr, scf, nullptr, HD, SEQ);
            softmax_k<<<SEQ, 256, 0, stream>>>(scf, pbh, pbl);
            // att[b] = P@v (split) -> split bf16 [2048][4096]
            gemm_nt<4, false, true><<<dim3(16, 32), 256, 0, stream>>>(
                pbh, pbl, vTh, vTl, nullptr,
                atth + (long)b * SEQ * HD, attl + (long)b * SEQ * HD, SEQ, HD);
        }

        // ---- phase 2 weights: wo, w1, w2 (wq/wk/wv dead) ----
        bf16 *woH = slot[0], *woL = slot[1], *w1H = slot[2], *w1L = slot[3],
             *w2H = slot[4], *w2L = slot[5];
        transpose_k<<<dim3(16, 64), 256, 0, stream>>>(wo + l * TSZ, woH, woL, HD, DM);
        transpose_k<<<dim3(64, 16), 256, 0, stream>>>(w1 + l * TSZ, w1H, w1L, DM, HD);
        transpose_k<<<dim3(16, 64), 256, 0, stream>>>(w2 + l * TSZ, w2H, w2L, HD, DM);

        // attout = att@wo + bo (split) -> f32 [8192][1024]
        gemm_nt<0, true, true><<<dim3(64, 8), 256, 0, stream>>>(
            atth, attl, woH, woL, bo + l * DM, attout, nullptr, HD, DM);
        // LN1(y + attout)
        ln_stats_k<<<dim3(64, NB), 256, 0, stream>>>(yf, attout, part);
        ln_fin_k  <<<NB, 64, 0, stream>>>(part, stats);
        ln_apply_k<<<8192, 256, 0, stream>>>(yf, attout, ln1w + (long)l * SD, ln1b + (long)l * SD,
                                             stats, yf, ybh, ybl);
        // h = y@w1 + b1 (split) -> split bf16 [8192][4096] (att region, now dead)
        gemm_nt<4, true, true><<<dim3(64, 32), 256, 0, stream>>>(
            ybh, ybl, w1H, w1L, b1 + l * HD, hh, hl, DM, HD);
        // ffn = gelu(h@w2 + b2) (split) -> f32 [8192][1024]
        gemm_nt<1, true, true><<<dim3(64, 8), 256, 0, stream>>>(
            hh, hl, w2H, w2L, b2 + l * DM, ffnf, nullptr, HD, DM);
        // LN2(y + ffn); final layer writes f32 straight to d_out
        float* yout_dst = (l == 1) ? (float*)d_out : yf;
        ln_stats_k<<<dim3(64, NB), 256, 0, stream>>>(yf, ffnf, part);
        ln_fin_k  <<<NB, 64, 0, stream>>>(part, stats);
        ln_apply_k<<<8192, 256, 0, stream>>>(yf, ffnf, ln2w + (long)l * SD, ln2b + (long)l * SD,
                                             stats, yout_dst, ybh, ybl);
    }
}

// Round 8
// 3934.976 us; speedup vs baseline: 1.4311x; 1.4311x over previous
//
#include <hip/hip_runtime.h>
#include <cstdint>
#include <cstddef>

using bf16 = __bf16;
typedef float f32x4 __attribute__((ext_vector_type(4)));
typedef bf16 bf16x8 __attribute__((ext_vector_type(8)));
typedef bf16 bf16x4 __attribute__((ext_vector_type(4)));

#define NB 4           // batch
#define SEQ 2048
#define DM 1024        // d_model
#define HD 4096        // hidden
#define SD (SEQ*DM)    // 2^21 elems per sample

__device__ __forceinline__ float geluf(float v) {
    return 0.5f * v * (1.0f + erff(v * 0.70710678118654752f));
}

#define GLL(gp, lp) __builtin_amdgcn_global_load_lds( \
    (const __attribute__((address_space(1))) void*)(gp), \
    (__attribute__((address_space(3))) void*)(lp), 16, 0, 0)

// ---------------------------------------------------------------------------
// Split-precision NT GEMM, FUSED 3-pass:
//   C = (Ah+Al) @ (Bh+Bl)^T  ~=  Ah*Bh + Al*Bh + Ah*Bl   (f32 accum)
// A: M x K row-major bf16 pair, Bt: N x K row-major bf16 pair (K-contiguous).
// Tile 128x128x64, 4 waves, 16x16x32 bf16 MFMA. All 4 tiles (Ah,Al,Bh,Bl)
// resident in LDS per K-step -> 48 MFMAs per barrier pair (vs 16), staging
// fetched once. Chunk XOR swizzle (c' = c ^ (m&7)) on BOTH the global source
// and the ds_read address (both-sides involution).
// EPI: 0 = f32 store, 1 = f32 gelu store,
//      4 = split bf16 (hi+lo) store, 5 = split bf16 transposed store (V^T)
// ---------------------------------------------------------------------------
template<int EPI, bool BIAS>
__global__ __launch_bounds__(256, 2) void gemm3_nt(
    const bf16* __restrict__ Ah, const bf16* __restrict__ Al,
    const bf16* __restrict__ Bh, const bf16* __restrict__ Bl,
    const float* __restrict__ bias, void* __restrict__ Cg, void* __restrict__ Cl,
    const int K, const int ldc, const long sA, const long sB, const long sC)
{
    __shared__ __align__(16) bf16 smAh[128 * 64];
    __shared__ __align__(16) bf16 smAl[128 * 64];
    __shared__ __align__(16) bf16 smBh[128 * 64];
    __shared__ __align__(16) bf16 smBl[128 * 64];

    const int tid  = threadIdx.x;
    const int lane = tid & 63;
    const int wave = tid >> 6;
    const int wr   = (wave >> 1) << 6;
    const int wc   = (wave & 1) << 6;
    const int l15  = lane & 15;
    const int q4   = lane >> 4;

    const long aoff = (long)blockIdx.z * sA + (long)blockIdx.x * 128 * K;
    const long boff = (long)blockIdx.z * sB + (long)blockIdx.y * 128 * K;
    const bf16* pAh = Ah + aoff;
    const bf16* pAl = Al + aoff;
    const bf16* pBh = Bh + boff;
    const bf16* pBl = Bl + boff;

    // staging: chunk = it*256 + tid; row m = chunk>>3;
    // global chunk col = (chunk&7) ^ (m&7)  (pre-swizzled source)
    int srow[4], scol[4];
#pragma unroll
    for (int it = 0; it < 4; ++it) {
        int chunk = it * 256 + tid;
        int m = chunk >> 3;
        srow[it] = m;
        scol[it] = ((chunk & 7) ^ (m & 7)) * 8;
    }

    f32x4 acc[4][4] = {};

    for (int k0 = 0; k0 < K; k0 += 64) {
#pragma unroll
        for (int it = 0; it < 4; ++it) {
            const long go = (long)srow[it] * K + (k0 + scol[it]);
            const size_t lo = (size_t)(it * 256 + (wave << 6)) * 8;   // linear fill
            GLL(pAh + go, smAh + lo);
            GLL(pAl + go, smAl + lo);
            GLL(pBh + go, smBh + lo);
            GLL(pBl + go, smBl + lo);
        }
        __syncthreads();   // compiler drains vmcnt(0) before barrier

#pragma unroll
        for (int kk = 0; kk < 2; ++kk) {
            bf16x8 avh[4], avl[4], bvh[4], bvl[4];
#pragma unroll
            for (int i = 0; i < 4; ++i) {
                const int rowa = wr + i * 16 + l15;
                const int ca = ((kk * 4 + q4) ^ (rowa & 7)) * 8;   // swizzled read
                avh[i] = *(const bf16x8*)(smAh + rowa * 64 + ca);
                avl[i] = *(const bf16x8*)(smAl + rowa * 64 + ca);
                const int rowb = wc + i * 16 + l15;
                const int cb = ((kk * 4 + q4) ^ (rowb & 7)) * 8;
                bvh[i] = *(const bf16x8*)(smBh + rowb * 64 + cb);
                bvl[i] = *(const bf16x8*)(smBl + rowb * 64 + cb);
            }
#pragma unroll
            for (int i = 0; i < 4; ++i)
#pragma unroll
                for (int j = 0; j < 4; ++j) {
                    acc[i][j] = __builtin_amdgcn_mfma_f32_16x16x32_bf16(
                        avh[i], bvh[j], acc[i][j], 0, 0, 0);
                    acc[i][j] = __builtin_amdgcn_mfma_f32_16x16x32_bf16(
                        avl[i], bvh[j], acc[i][j], 0, 0, 0);
                    acc[i][j] = __builtin_amdgcn_mfma_f32_16x16x32_bf16(
                        avh[i], bvl[j], acc[i][j], 0, 0, 0);
                }
        }
        __syncthreads();
    }

    // epilogue: D col = lane&15, row = (lane>>4)*4 + e
    const long zC = (long)blockIdx.z * sC;
    const int gcol0 = blockIdx.y * 128 + wc + l15;
    const int grow0 = blockIdx.x * 128 + wr + q4 * 4;
#pragma unroll
    for (int j = 0; j < 4; ++j) {
        const int col = gcol0 + j * 16;
        const float bvz = BIAS ? bias[col] : 0.0f;
#pragma unroll
        for (int i = 0; i < 4; ++i) {
            const int row = grow0 + i * 16;
            if (EPI == 5) {
                bf16x4 oh, ol;
#pragma unroll
                for (int e = 0; e < 4; ++e) {
                    const float v = acc[i][j][e] + bvz;
                    const bf16 hi = (bf16)v;
                    oh[e] = hi;
                    ol[e] = (bf16)(v - (float)hi);
                }
                *(bf16x4*)((bf16*)Cg + zC + (long)col * ldc + row) = oh;
                *(bf16x4*)((bf16*)Cl + zC + (long)col * ldc + row) = ol;
            } else {
#pragma unroll
                for (int e = 0; e < 4; ++e) {
                    float v = acc[i][j][e] + bvz;
                    if (EPI == 1) v = geluf(v);
                    const long off = zC + (long)(row + e) * ldc + col;
                    if (EPI == 4) {
                        const bf16 hi = (bf16)v;
                        ((bf16*)Cg)[off] = hi;
                        ((bf16*)Cl)[off] = (bf16)(v - (float)hi);
                    } else {
                        ((float*)Cg)[off] = v;
                    }
                }
            }
        }
    }
}

// ---------------------------------------------------------------------------
// y = emb[x] (f32) + sinusoidal pos -> split bf16 (hi, lo) residual
// ---------------------------------------------------------------------------
__global__ __launch_bounds__(256) void embed_k(
    const int* __restrict__ x, const float* __restrict__ emb,
    bf16* __restrict__ yh, bf16* __restrict__ yl)
{
    const int bs = blockIdx.x;          // B*S
    const int s = bs & (SEQ - 1);
    const long e0 = (long)x[bs] * DM;
    const int d = threadIdx.x * 4;
    const float4 ev = *(const float4*)(emb + e0 + d);
    float o[4];
    const float fs = (float)s;
#pragma unroll
    for (int e = 0; e < 4; ++e) {
        const int dd = d + e;
        const float div = powf(10000.0f, (float)dd * (1.0f / 1024.0f));
        const float ang = fs / div;
        const float p = (dd & 1) ? cosf(ang) : sinf(ang);
        o[e] = ((const float*)&ev)[e] + p;
    }
    bf16x4 oh, ol;
#pragma unroll
    for (int e = 0; e < 4; ++e) {
        oh[e] = (bf16)o[e];
        ol[e] = (bf16)(o[e] - (float)oh[e]);
    }
    *(bf16x4*)(yh + (long)bs * DM + d) = oh;
    *(bf16x4*)(yl + (long)bs * DM + d) = ol;
}

// ---------------------------------------------------------------------------
// f32 -> split bf16 transpose: src R x C (f32) -> dst C x R (hi, lo)
// ---------------------------------------------------------------------------
__global__ __launch_bounds__(256) void transpose_k(
    const float* __restrict__ src, bf16* __restrict__ dsth, bf16* __restrict__ dstl,
    int R, int C)
{
    __shared__ bf16 th[64][65];
    __shared__ bf16 tl[64][65];
    const int c0 = blockIdx.x * 64, r0 = blockIdx.y * 64;
    const int t = threadIdx.x;
    const int tr = t >> 4;
    const int tc = (t & 15) * 4;
#pragma unroll
    for (int p = 0; p < 4; ++p) {
        const int r = tr + p * 16;
        const float4 v = *(const float4*)(src + (long)(r0 + r) * C + c0 + tc);
        const float vv[4] = {v.x, v.y, v.z, v.w};
#pragma unroll
        for (int e = 0; e < 4; ++e) {
            const bf16 hi = (bf16)vv[e];
            th[r][tc + e] = hi;
            tl[r][tc + e] = (bf16)(vv[e] - (float)hi);
        }
    }
    __syncthreads();
#pragma unroll
    for (int p = 0; p < 4; ++p) {
        const int c = tr + p * 16;
        bf16x4 oh, ol;
#pragma unroll
        for (int e = 0; e < 4; ++e) { oh[e] = th[tc + e][c]; ol[e] = tl[tc + e][c]; }
        *(bf16x4*)(dsth + (long)(c0 + c) * R + r0 + tc) = oh;
        *(bf16x4*)(dstl + (long)(c0 + c) * R + r0 + tc) = ol;
    }
}

// ---------------------------------------------------------------------------
// Row softmax: 2048 f32 per row -> split bf16 (hi, lo)
// ---------------------------------------------------------------------------
__global__ __launch_bounds__(256) void softmax_k(
    const float* __restrict__ S, bf16* __restrict__ Ph, bf16* __restrict__ Pl)
{
    const long row = blockIdx.x;
    const float4* src = (const float4*)(S + (row << 11));
    const int t = threadIdx.x;
    float4 a = src[t], b = src[256 + t];
    float m = fmaxf(fmaxf(fmaxf(a.x, a.y), fmaxf(a.z, a.w)),
                    fmaxf(fmaxf(b.x, b.y), fmaxf(b.z, b.w)));
#pragma unroll
    for (int o = 32; o; o >>= 1) m = fmaxf(m, __shfl_xor(m, o));
    __shared__ float red1[4], red2[4];
    const int wv = t >> 6;
    if ((t & 63) == 0) red1[wv] = m;
    __syncthreads();
    m = fmaxf(fmaxf(red1[0], red1[1]), fmaxf(red1[2], red1[3]));

    a.x = expf(a.x - m); a.y = expf(a.y - m); a.z = expf(a.z - m); a.w = expf(a.w - m);
    b.x = expf(b.x - m); b.y = expf(b.y - m); b.z = expf(b.z - m); b.w = expf(b.w - m);
    float s = a.x + a.y + a.z + a.w + b.x + b.y + b.z + b.w;
#pragma unroll
    for (int o = 32; o; o >>= 1) s += __shfl_xor(s, o);
    if ((t & 63) == 0) red2[wv] = s;
    __syncthreads();
    s = red2[0] + red2[1] + red2[2] + red2[3];
    const float inv = 1.0f / s;

    const float pv[8] = {a.x * inv, a.y * inv, a.z * inv, a.w * inv,
                         b.x * inv, b.y * inv, b.z * inv, b.w * inv};
    bf16x4 h0, l0, h1, l1;
#pragma unroll
    for (int e = 0; e < 4; ++e) {
        const bf16 hi = (bf16)pv[e];
        h0[e] = hi; l0[e] = (bf16)(pv[e] - (float)hi);
        const bf16 hj = (bf16)pv[4 + e];
        h1[e] = hj; l1[e] = (bf16)(pv[4 + e] - (float)hj);
    }
    *(bf16x4*)(Ph + (row << 11) + t * 4) = h0;
    *(bf16x4*)(Pl + (row << 11) + t * 4) = l0;
    *(bf16x4*)(Ph + (row << 11) + 1024 + t * 4) = h1;
    *(bf16x4*)(Pl + (row << 11) + 1024 + t * 4) = l1;
}

// ---------------------------------------------------------------------------
// LayerNorm over whole (S,D) sample; residual carried as split bf16 (hi+lo).
// ---------------------------------------------------------------------------
__global__ __launch_bounds__(256) void ln_stats_k(
    const bf16* __restrict__ yh, const bf16* __restrict__ yl,
    const float* __restrict__ r, float2* __restrict__ part)
{
    const int b = blockIdx.y;
    const long base = (long)b * SD + (long)blockIdx.x * (SD / 64);
    float s = 0.f, q = 0.f;
    for (int i = threadIdx.x; i < (SD / 64) / 4; i += 256) {
        const bf16x4 h = *(const bf16x4*)(yh + base + i * 4);
        const bf16x4 l = *(const bf16x4*)(yl + base + i * 4);
        const float4 c = *(const float4*)(r + base + i * 4);
        const float cc[4] = {c.x, c.y, c.z, c.w};
#pragma unroll
        for (int e = 0; e < 4; ++e) {
            const float x = (float)h[e] + (float)l[e] + cc[e];
            s += x; q += x * x;
        }
    }
#pragma unroll
    for (int o = 32; o; o >>= 1) { s += __shfl_xor(s, o); q += __shfl_xor(q, o); }
    __shared__ float rs[4], rq[4];
    const int wv = threadIdx.x >> 6;
    if ((threadIdx.x & 63) == 0) { rs[wv] = s; rq[wv] = q; }
    __syncthreads();
    if (threadIdx.x == 0)
        part[b * 64 + blockIdx.x] = make_float2(rs[0] + rs[1] + rs[2] + rs[3],
                                                rq[0] + rq[1] + rq[2] + rq[3]);
}

__global__ void ln_fin_k(const float2* __restrict__ part, float2* __restrict__ stats)
{
    const int b = blockIdx.x;
    const float2 p = part[b * 64 + threadIdx.x];
    float s = p.x, q = p.y;
#pragma unroll
    for (int o = 32; o; o >>= 1) { s += __shfl_xor(s, o); q += __shfl_xor(q, o); }
    if (threadIdx.x == 0) {
        const float inv_n = 1.0f / (float)SD;
        const float mean = s * inv_n;
        const float var = fmaxf(q * inv_n - mean * mean, 0.f);
        stats[b] = make_float2(mean, rsqrtf(var + 1e-5f));
    }
}

__global__ __launch_bounds__(256) void ln_apply_k(
    const bf16* __restrict__ yh_in, const bf16* __restrict__ yl_in,
    const float* __restrict__ r,
    const float* __restrict__ w, const float* __restrict__ bb,
    const float2* __restrict__ stats,
    bf16* __restrict__ yh_out, bf16* __restrict__ yl_out, float* __restrict__ fout)
{
    const long i = ((long)blockIdx.x * 256 + threadIdx.x) * 4;
    const int smp = (int)(i >> 21);
    const long sd = i & (SD - 1);
    const float2 st = stats[smp];
    const bf16x4 h = *(const bf16x4*)(yh_in + i);
    const bf16x4 l = *(const bf16x4*)(yl_in + i);
    const float4 c = *(const float4*)(r + i);
    const float4 wv = *(const float4*)(w + sd);
    const float4 bv = *(const float4*)(bb + sd);
    const float cc[4] = {c.x, c.y, c.z, c.w};
    const float ww[4] = {wv.x, wv.y, wv.z, wv.w};
    const float bbx[4] = {bv.x, bv.y, bv.z, bv.w};
    float o[4];
#pragma unroll
    for (int e = 0; e < 4; ++e) {
        const float x = (float)h[e] + (float)l[e] + cc[e];
        o[e] = (x - st.x) * st.y * ww[e] + bbx[e];
    }
    bf16x4 oh, ol;
#pragma unroll
    for (int e = 0; e < 4; ++e) {
        oh[e] = (bf16)o[e];
        ol[e] = (bf16)(o[e] - (float)oh[e]);
    }
    *(bf16x4*)(yh_out + i) = oh;
    *(bf16x4*)(yl_out + i) = ol;
    if (fout != nullptr) *(float4*)(fout + i) = *(float4*)o;
}

// ---------------------------------------------------------------------------
extern "C" void kernel_launch(void* const* d_in, const int* in_sizes, int n_in,
                              void* d_out, int out_size, void* d_ws, size_t ws_size,
                              hipStream_t stream)
{
    (void)in_sizes; (void)n_in; (void)out_size; (void)ws_size;

    const int*   x    = (const int*)  d_in[0];
    const float* emb  = (const float*)d_in[1];
    const float* wq   = (const float*)d_in[2];
    const float* bq   = (const float*)d_in[3];
    const float* wk   = (const float*)d_in[4];
    const float* bk   = (const float*)d_in[5];
    const float* wv   = (const float*)d_in[6];
    const float* bv   = (const float*)d_in[7];
    const float* wo   = (const float*)d_in[8];
    const float* bo   = (const float*)d_in[9];
    const float* w1   = (const float*)d_in[10];
    const float* b1   = (const float*)d_in[11];
    const float* w2   = (const float*)d_in[12];
    const float* b2   = (const float*)d_in[13];
    const float* ln1w = (const float*)d_in[14];
    const float* ln1b = (const float*)d_in[15];
    const float* ln2w = (const float*)d_in[16];
    const float* ln2b = (const float*)d_in[17];

    // Workspace — peak 368 MiB + 16 KiB (round-2 proved ≥385 MiB usable).
    char* ws = (char*)d_ws;
    const size_t MB = (size_t)1 << 20;
    bf16*   ybh   = (bf16*) (ws);                  //  16 MiB residual hi
    bf16*   ybl   = (bf16*) (ws + 16  * MB);       //  16 MiB residual lo
    bf16*   wT    = (bf16*) (ws + 32  * MB);       //  48 MiB: 6 x 8 MiB weight slots
    bf16*   atth  = (bf16*) (ws + 80  * MB);       //  64 MiB att hi [8192][4096]
    bf16*   attl  = (bf16*) (ws + 144 * MB);       //  64 MiB att lo
    // per-half (2-batch) attention scratch, 208..368:
    bf16*   qh    = (bf16*) (ws + 208 * MB);       //  32 MiB [2][2048][4096]
    bf16*   ql    = (bf16*) (ws + 240 * MB);       //  32 MiB
    bf16*   kh    = (bf16*) (ws + 272 * MB);       //  32 MiB
    bf16*   kl    = (bf16*) (ws + 304 * MB);       //  32 MiB
    float*  scf   = (float*)(ws + 336 * MB);       //  32 MiB f32 [2][2048][2048]
    bf16*   pbh   = (bf16*) (ws + 208 * MB);       //  16 MiB probs hi  (q dead)
    bf16*   pbl   = (bf16*) (ws + 224 * MB);       //  16 MiB probs lo
    bf16*   vTh   = (bf16*) (ws + 272 * MB);       //  32 MiB V^T hi    (k dead)
    bf16*   vTl   = (bf16*) (ws + 304 * MB);       //  32 MiB V^T lo
    // post-attention f32 outputs (per-half region dead):
    float*  attout= (float*)(ws + 208 * MB);       //  32 MiB f32 [8192][1024]
    float*  ffnf  = (float*)(ws + 208 * MB);       //  32 MiB f32
    bf16*   hh    = atth;                          //  64 MiB h hi (att dead after O-proj)
    bf16*   hl    = attl;                          //  64 MiB h lo
    float2* part  = (float2*)(ws + 368 * MB);      //  LN partials
    float2* stats = (float2*)(ws + 368 * MB + 8192);

    const long TSZ = (long)DM * HD;
    bf16* slot[6];
    for (int s = 0; s < 6; ++s) slot[s] = wT + (long)s * TSZ;

    embed_k<<<NB * SEQ, 256, 0, stream>>>(x, emb, ybh, ybl);

    for (int l = 0; l < 2; ++l) {
        // ---- phase 1 weights: wq, wk, wv (split, K-contiguous) ----
        bf16 *wqH = slot[0], *wqL = slot[1], *wkH = slot[2], *wkL = slot[3],
             *wvH = slot[4], *wvL = slot[5];
        transpose_k<<<dim3(64, 16), 256, 0, stream>>>(wq + l * TSZ, wqH, wqL, DM, HD);
        transpose_k<<<dim3(64, 16), 256, 0, stream>>>(wk + l * TSZ, wkH, wkL, DM, HD);
        transpose_k<<<dim3(64, 16), 256, 0, stream>>>(wv + l * TSZ, wvH, wvL, DM, HD);

        // ---- attention in two 2-batch halves (z = batch within half) ----
        for (int h2 = 0; h2 < 2; ++h2) {
            const long yofs = (long)(2 * h2) * SD;
            // q = y@wq + bq : grid (16,32,2)
            gemm3_nt<4, true><<<dim3(16, 32, 2), 256, 0, stream>>>(
                ybh + yofs, ybl + yofs, wqH, wqL, bq + l * HD, qh, ql,
                DM, HD, SD, 0, (long)SEQ * HD);
            // k = y@wk + bk
            gemm3_nt<4, true><<<dim3(16, 32, 2), 256, 0, stream>>>(
                ybh + yofs, ybl + yofs, wkH, wkL, bk + l * HD, kh, kl,
                DM, HD, SD, 0, (long)SEQ * HD);
            // scores = q@k^T -> f32 : grid (16,16,2), 512 blocks (2/CU)
            gemm3_nt<0, false><<<dim3(16, 16, 2), 256, 0, stream>>>(
                qh, ql, kh, kl, nullptr, scf, nullptr,
                HD, SEQ, (long)SEQ * HD, (long)SEQ * HD, (long)SEQ * SEQ);
            // softmax -> split probs (into dead q region)
            softmax_k<<<2 * SEQ, 256, 0, stream>>>(scf, pbh, pbl);
            // v = y@wv + bv, split transposed -> vT (into dead k region)
            gemm3_nt<5, true><<<dim3(16, 32, 2), 256, 0, stream>>>(
                ybh + yofs, ybl + yofs, wvH, wvL, bv + l * HD, vTh, vTl,
                DM, SEQ, SD, 0, (long)HD * SEQ);
            // att = P@V -> split bf16
            gemm3_nt<4, false><<<dim3(16, 32, 2), 256, 0, stream>>>(
                pbh, pbl, vTh, vTl, nullptr,
                atth + yofs * 4, attl + yofs * 4,
                SEQ, HD, (long)SEQ * SEQ, (long)HD * SEQ, (long)SEQ * HD);
        }

        // ---- phase 2 weights: wo, w1, w2 (wq/wk/wv dead) ----
        bf16 *woH = slot[0], *woL = slot[1], *w1H = slot[2], *w1L = slot[3],
             *w2H = slot[4], *w2L = slot[5];
        transpose_k<<<dim3(16, 64), 256, 0, stream>>>(wo + l * TSZ, woH, woL, HD, DM);
        transpose_k<<<dim3(64, 16), 256, 0, stream>>>(w1 + l * TSZ, w1H, w1L, DM, HD);
        transpose_k<<<dim3(16, 64), 256, 0, stream>>>(w2 + l * TSZ, w2H, w2L, HD, DM);

        // attout = att@wo + bo -> f32 [8192][1024]
        gemm3_nt<0, true><<<dim3(64, 8, 1), 256, 0, stream>>>(
            atth, attl, woH, woL, bo + l * DM, attout, nullptr,
            HD, DM, 0, 0, 0);
        // LN1(y + attout)
        ln_stats_k<<<dim3(64, NB), 256, 0, stream>>>(ybh, ybl, attout, part);
        ln_fin_k  <<<NB, 64, 0, stream>>>(part, stats);
        ln_apply_k<<<8192, 256, 0, stream>>>(ybh, ybl, attout,
                                             ln1w + (long)l * SD, ln1b + (long)l * SD,
                                             stats, ybh, ybl, nullptr);
        // h = y@w1 + b1 -> split bf16 [8192][4096] (att region, now dead)
        gemm3_nt<4, true><<<dim3(64, 32, 1), 256, 0, stream>>>(
            ybh, ybl, w1H, w1L, b1 + l * HD, hh, hl, DM, HD, 0, 0, 0);
        // ffn = gelu(h@w2 + b2) -> f32 [8192][1024]
        gemm3_nt<1, true><<<dim3(64, 8, 1), 256, 0, stream>>>(
            hh, hl, w2H, w2L, b2 + l * DM, ffnf, nullptr, HD, DM, 0, 0, 0);
        // LN2(y + ffn); final layer also writes f32 to d_out
        float* fdst = (l == 1) ? (float*)d_out : nullptr;
        ln_stats_k<<<dim3(64, NB), 256, 0, stream>>>(ybh, ybl, ffnf, part);
        ln_fin_k  <<<NB, 64, 0, stream>>>(part, stats);
        ln_apply_k<<<8192, 256, 0, stream>>>(ybh, ybl, ffnf,
                                             ln2w + (long)l * SD, ln2b + (long)l * SD,
                                             stats, ybh, ybl, fdst);
    }
}